// Round 3
// baseline (232.510 us; speedup 1.0000x reference)
//
#include <hip/hip_runtime.h>

// TopologyAwareAttention — R12: single-node fused, with R11's two failure
// mechanisms fixed (rocprof-diagnosed):
//  (1) R11 VGPR=40 => compiler sank the attn prefetch; fix: stage attn slice
//      to LDS at kernel start (regs die immediately, can't be sunk).
//  (2) R11 argmax read ref per-thread-sequential => 64 distinct 64B lines per
//      wave instruction (4x transaction amplification, request-rate-bound);
//      fix: coalesced global -> LDS bounce (36-query chunks, dbuf, stride-65
//      padding), per-thread-sequential reads then hit LDS, not L1/L2.
//  f(t) = sum_e relu(t*w1[e]+b1[e]) * mean_h(w2[e,h]) + mean(b2)
//  centers on 16x16 grid => d2 in [0,450] => 451-entry LUT
//  mean dist via cell histogram: sum = SUM_{c1,c2} h[c1] h[c2] sqrt(d2)
// Stats float chains verbatim from R9/R10 (absmax bit-identical). Argmax is
// exact first-max: parts processed in element order, strict-> across, first-
// equal within f4, quad combine tie-breaks to lower index.

#define NQ      900
#define LUT_N   451
#define CHUNK_Q 36          // queries per chunk; 25 chunks exactly
#define NCHUNK  25
#define RPAD    65          // f4 stride per query in LDS (64 + 1 pad)

// LDS carve (bytes): attn_s 32768 | ref_s 74880 | sqs 1808 | w1s 1024 |
// b1s 1024 | wbars 1024 | lut_s 1808 | wsum 16 | cpk 912 | hsh 1024 | centb 912
#define SMEM_BYTES 117200

#define ARGSTEP(V, BV, BI, K)                                               \
    {                                                                       \
        float m01_ = fmaxf((V).x, (V).y);                                   \
        float m23_ = fmaxf((V).z, (V).w);                                   \
        float m_   = fmaxf(m01_, m23_);                                     \
        if (m_ > (BV)) {                                                    \
            (BV) = m_;                                                      \
            int kb_ = (K) * 4;                                              \
            (BI) = ((V).x == m_) ? kb_                                      \
                 : ((V).y == m_) ? kb_ + 1                                  \
                 : ((V).z == m_) ? kb_ + 2 : kb_ + 3;                       \
        }                                                                   \
    }

__global__ __launch_bounds__(256)
void k_fused(const float* __restrict__ attn,
             const float* __restrict__ ref,
             const float* __restrict__ lam_p,
             const float* __restrict__ w1,
             const float* __restrict__ b1,
             const float* __restrict__ w2,
             const float* __restrict__ b2,
             float* __restrict__ out) {
    extern __shared__ char smem[];
    float4*        attn_s = (float4*)smem;                    // 2048 f4
    float4*        ref_s  = (float4*)(smem + 32768);          // 2*36*65 f4
    float*         sqs    = (float*)(smem + 107648);
    float*         w1s    = (float*)(smem + 109456);
    float*         b1s    = (float*)(smem + 110480);
    float*         wbars  = (float*)(smem + 111504);
    float*         lut_s  = (float*)(smem + 112528);
    float*         wsum   = (float*)(smem + 114336);
    int*           cpk    = (int*)(smem + 114352);
    int*           hsh    = (int*)(smem + 115264);
    unsigned char* centb  = (unsigned char*)(smem + 116288);

    const int tid  = threadIdx.x;
    const int lane = tid & 63;
    const int wave = tid >> 6;
    const int b    = blockIdx.y;

    // ---- attn slice: global -> regs (issued first) ----
    const float4* attn4 = (const float4*)attn;
    const int f4l = blockIdx.x * 2048 + tid;           // batch-local float4 idx
    float4 areg[8];
    #pragma unroll
    for (int u = 0; u < 8; ++u) {
        int f4 = f4l + u * 256;
        int cf4 = f4 < 202500 ? f4 : 202499;           // clamp; store guarded
        areg[u] = attn4[(size_t)b * 202500 + cf4];
    }

    // ---- LDS const setup (overlaps attn load latency) ----
    hsh[tid] = 0;
    w1s[tid] = w1[tid];
    b1s[tid] = b1[tid];
    {
        float s8 = 0.f;
        #pragma unroll
        for (int h = 0; h < 8; ++h) s8 += w2[tid * 8 + h];
        wbars[tid] = s8 * 0.125f;
    }
    for (int s = tid; s < LUT_N; s += 256) sqs[s] = sqrtf((float)s);

    // ---- chunk-0 ref prefetch (coalesced: consecutive threads = consecutive
    //      16B; idx = i*256+tid -> q = idx>>6 wave-uniform, e4 = lane) ----
    const float4* ref4 = (const float4*)ref + (size_t)b * 57600;  // 900*64
    float4 creg[9];
    #pragma unroll
    for (int i = 0; i < 9; ++i) {
        int idx = i * 256 + tid;
        creg[i] = ref4[(size_t)((idx >> 6)) * 64 + (idx & 63)];
    }

    // ---- attn regs -> LDS (kills the registers; cannot be sunk) ----
    #pragma unroll
    for (int u = 0; u < 8; ++u) attn_s[tid + u * 256] = areg[u];

    // ---- chunk loop: dbuf, 1 barrier/chunk ----
    for (int c = 0; c < NCHUNK; ++c) {
        float4* buf = ref_s + (c & 1) * (CHUNK_Q * RPAD);
        #pragma unroll
        for (int i = 0; i < 9; ++i) {
            int idx = i * 256 + tid;
            buf[(idx >> 6) * RPAD + (idx & 63)] = creg[i];
        }
        if (c < NCHUNK - 1) {
            #pragma unroll
            for (int i = 0; i < 9; ++i) {
                int idx = i * 256 + tid;
                creg[i] = ref4[(size_t)((c + 1) * CHUNK_Q + (idx >> 6)) * 64
                               + (idx & 63)];
            }
        }
        __syncthreads();
        if (tid < CHUNK_Q * 4) {                        // 4 threads per query
            int q = tid >> 2, part = tid & 3;
            const float4* rq = buf + q * RPAD + part * 16;
            float bv = -1e38f;
            int   bi = 0;
            #pragma unroll
            for (int j = 0; j < 16; ++j) {
                float4 v = rq[j];
                ARGSTEP(v, bv, bi, part * 16 + j)
            }
            #pragma unroll
            for (int off = 2; off >= 1; off >>= 1) {    // quad combine
                float ov = __shfl_down(bv, off, 64);
                int   oi = __shfl_down(bi, off, 64);
                if (ov > bv || (ov == bv && oi < bi)) { bv = ov; bi = oi; }
            }
            if (part == 0) centb[c * CHUNK_Q + q] = (unsigned char)bi;
        }
        // no 2nd barrier: next iter writes the OTHER buffer; the next
        // iteration's __syncthreads orders write(c+2) after reduce(c).
    }
    __syncthreads();

    // ---- pack centers + histogram ----
    if (tid < 225)
        cpk[tid] = (int)centb[4 * tid]            | ((int)centb[4 * tid + 1] << 8) |
                   ((int)centb[4 * tid + 2] << 16) | ((int)centb[4 * tid + 3] << 24);
    for (int k = tid; k < NQ; k += 256) atomicAdd(&hsh[centb[k]], 1);
    __syncthreads();

    // ---- pairwise mean via cell histogram (verbatim) ----
    float local = 0.f;
    {
        int h2v = hsh[tid];                             // thread owns c2 = tid
        if (h2v) {
            int ix2 = tid & 15, iy2 = tid >> 4;
            for (int c1 = 0; c1 < 256; ++c1) {
                int h1 = hsh[c1];                       // broadcast read
                int dx = (c1 & 15) - ix2;
                int dy = (c1 >> 4) - iy2;
                local += (float)h1 * sqs[dx * dx + dy * dy];
            }
            local *= (float)h2v;
        }
    }
    #pragma unroll
    for (int off = 32; off >= 1; off >>= 1) local += __shfl_down(local, off, 64);
    if (lane == 0) wsum[wave] = local;
    __syncthreads();

    float tot   = wsum[0] + wsum[1] + wsum[2] + wsum[3];
    float mean  = tot * (1.f / 15.f) * (1.f / ((float)NQ * (float)NQ));
    float inv   = 1.f / (mean + 1e-6f);
    float b2bar = 0.125f * (b2[0] + b2[1] + b2[2] + b2[3] +
                            b2[4] + b2[5] + b2[6] + b2[7]);
    float lam   = lam_p[0];

    // ---- LUT: entries tid and tid+256, interleaved loop (verbatim) ----
    {
        float t0   = sqs[tid] * (1.f / 15.f) * inv;
        bool  has1 = (tid + 256 < LUT_N);               // tid < 195
        float t1   = has1 ? sqs[tid + 256] * (1.f / 15.f) * inv : 0.f;
        float acc0 = b2bar, acc1 = b2bar;
        for (int i = 0; i < 256; ++i) {
            float w  = w1s[i];
            float bb = b1s[i];
            float wb = wbars[i];
            float h0 = fmaf(t0, w, bb);
            acc0 = fmaf(fmaxf(h0, 0.f), wb, acc0);
            float h1 = fmaf(t1, w, bb);
            acc1 = fmaf(fmaxf(h1, 0.f), wb, acc1);
        }
        lut_s[tid] = lam * acc0;
        if (has1) lut_s[tid + 256] = lam * acc1;
    }
    __syncthreads();

    // ---- apply + store (attn from LDS) ----
    float4* out4 = (float4*)out;
    #pragma unroll
    for (int u = 0; u < 8; ++u) {
        int f4 = f4l + u * 256;
        if (f4 < 202500) {
            int i  = (int)((unsigned)f4 / 225u);        // row 0..899
            int j4 = f4 - i * 225;                      // float4 within row
            int ci = (cpk[i >> 2] >> ((i & 3) * 8)) & 255;  // mostly broadcast
            int ixi = ci & 15, iyi = ci >> 4;
            int cw = cpk[j4];                           // stride-1, conflict-free
            float4 v = attn_s[tid + u * 256];
            int c, dx, dy;
            c = cw & 255;         dx = ixi - (c & 15); dy = iyi - (c >> 4); v.x += lut_s[dx*dx + dy*dy];
            c = (cw >> 8) & 255;  dx = ixi - (c & 15); dy = iyi - (c >> 4); v.y += lut_s[dx*dx + dy*dy];
            c = (cw >> 16) & 255; dx = ixi - (c & 15); dy = iyi - (c >> 4); v.z += lut_s[dx*dx + dy*dy];
            c = (cw >> 24) & 255; dx = ixi - (c & 15); dy = iyi - (c >> 4); v.w += lut_s[dx*dx + dy*dy];
            out4[(size_t)b * 202500 + f4] = v;
        }
    }
}

extern "C" void kernel_launch(void* const* d_in, const int* in_sizes, int n_in,
                              void* d_out, int out_size, void* d_ws, size_t ws_size,
                              hipStream_t stream) {
    const float* attn = (const float*)d_in[0];   // [2,900,900]
    const float* ref  = (const float*)d_in[1];   // [2,900,16,16]
    const float* lam  = (const float*)d_in[2];
    const float* w1   = (const float*)d_in[3];   // [256]
    const float* b1   = (const float*)d_in[4];   // [256]
    const float* w2   = (const float*)d_in[5];   // [256,8]
    const float* b2   = (const float*)d_in[6];   // [8]
    float* out = (float*)d_out;
    (void)d_ws; (void)ws_size;                   // no workspace needed

    // 117.2 KB dynamic LDS (> 64 KB static limit); host-side attr set is
    // graph-capture-legal (not a stream op).
    hipFuncSetAttribute((const void*)k_fused,
                        hipFuncAttributeMaxDynamicSharedMemorySize, SMEM_BYTES);
    k_fused<<<dim3(99, 2), 256, SMEM_BYTES, stream>>>(attn, ref, lam, w1, b1,
                                                      w2, b2, out);
}

// Round 4
// 83.666 us; speedup vs baseline: 2.7790x; 2.7790x over previous
//
#include <hip/hip_runtime.h>

// TopologyAwareAttention — R13 = revert to R9 (measured best, 83.68us).
// Session ledger: R10 (stats moved to k2) == R9 within fill noise; R11/R12
// (single-node fusion, two different implementations) lost 50-150us because
// redundant per-block work can't be latency-hidden at 1-block/CU occupancy
// and costs far more than the ~7us node it removes. Two kernels, poll
// handoff, is the structural optimum on this harness.
//  f(t) = sum_e relu(t*w1[e]+b1[e]) * mean_h(w2[e,h]) + mean(b2)
//  centers on 16x16 grid => d2 = dx^2+dy^2 in [0,450] => 451-entry LUT/batch
//  mean dist via cell histogram: sum = SUM_{c1,c2} h[c1] h[c2] sqrt(d2)
// K2 does 4 float4/thread (more MLP: outstanding loads, m13 pattern) +
// packed centers; K1 splits LUT across 2 stats blocks per batch (one
// inner-loop pass per thread). Tagged words: high16=0xC0DE, 0xAA poison
// can't match => relaxed polls only, validity rides with data.

#define NQ    900
#define LUT_N 451
#define TAG   0xC0DE0000u

__device__ __forceinline__ int aload_rlx(const int* p) {
    return __hip_atomic_load(p, __ATOMIC_RELAXED, __HIP_MEMORY_SCOPE_AGENT);
}
__device__ __forceinline__ void astore_rlx(int* p, int v) {
    __hip_atomic_store(p, v, __ATOMIC_RELAXED, __HIP_MEMORY_SCOPE_AGENT);
}

// ws layout (ints): cent2[900] tagged | lutp[2*451] | centp[2*225]
__global__ __launch_bounds__(256)
void k1_centers_stats(const float* __restrict__ ref,
                      const float* __restrict__ lam_p,
                      const float* __restrict__ w1,
                      const float* __restrict__ b1,
                      const float* __restrict__ w2,
                      const float* __restrict__ b2,
                      int* __restrict__ ws) {
    int*   cent2 = ws;
    float* lutp  = (float*)(ws + 900);
    int*   centp = ws + 900 + 2 * LUT_N;

    const int tid  = threadIdx.x;
    const int lane = tid & 63;
    const int wave = tid >> 6;
    const int blk  = blockIdx.x;

    if (blk < 450) {
        // ---- argmax: one wave per query, 4 queries per block ----
        __shared__ int ctmp[4];
        int q = blk * 4 + wave;                 // 0..1799
        const float* p = ref + (size_t)q * 256;
        float bv = p[lane];
        int   bi = lane;
        #pragma unroll
        for (int k = 1; k < 4; ++k) {
            float v = p[lane + 64 * k];
            if (v > bv) { bv = v; bi = lane + 64 * k; }   // strict > = first max
        }
        #pragma unroll
        for (int off = 32; off >= 1; off >>= 1) {
            float ov = __shfl_down(bv, off, 64);
            int   oi = __shfl_down(bi, off, 64);
            if (ov > bv || (ov == bv && oi < bi)) { bv = ov; bi = oi; }
        }
        if (lane == 0) ctmp[wave] = bi;         // iy*16+ix, fits u8
        __syncthreads();
        if (tid == 0) {
            // word blk*2 == b*450 + local_word (blocks 225.. are batch 1)
            astore_rlx(&cent2[blk*2+0], (int)(TAG | ((ctmp[0]&255)<<8) | (ctmp[1]&255)));
            astore_rlx(&cent2[blk*2+1], (int)(TAG | ((ctmp[2]&255)<<8) | (ctmp[3]&255)));
        }
        return;
    }

    // ---- stats: blocks 450..453 = (batch 0 half 0/1, batch 1 half 0/1) ----
    const int sb   = blk - 450;
    const int b    = sb >> 1;
    const int half = sb & 1;

    __shared__ int   idx_s[NQ];
    __shared__ float sqs[LUT_N];
    __shared__ int   hsh[256];
    __shared__ float w1s[256], b1s[256], wbars[256];
    __shared__ float wsum[4];

    hsh[tid] = 0;
    w1s[tid] = w1[tid];
    b1s[tid] = b1[tid];
    {
        float s8 = 0.f;
        #pragma unroll
        for (int h = 0; h < 8; ++h) s8 += w2[tid * 8 + h];
        wbars[tid] = s8 * 0.125f;
    }
    for (int s = tid; s < LUT_N; s += 256) sqs[s] = sqrtf((float)s);

    for (int k = tid; k < 450; k += 256) {      // <=2 distinct words per thread
        int w;
        while (((unsigned)(w = aload_rlx(&cent2[b * 450 + k])) & 0xFFFF0000u) != TAG)
            __builtin_amdgcn_s_sleep(1);
        idx_s[2 * k]     = (w >> 8) & 255;
        idx_s[2 * k + 1] =  w       & 255;
    }
    __syncthreads();

    for (int k = tid; k < NQ; k += 256) atomicAdd(&hsh[idx_s[k]], 1);
    __syncthreads();

    float local = 0.f;
    {
        int h2v = hsh[tid];                     // thread owns c2 = tid
        if (h2v) {
            int ix2 = tid & 15, iy2 = tid >> 4;
            for (int c1 = 0; c1 < 256; ++c1) {
                int h1 = hsh[c1];               // broadcast read
                int dx = (c1 & 15) - ix2;
                int dy = (c1 >> 4) - iy2;
                local += (float)h1 * sqs[dx * dx + dy * dy];
            }
            local *= (float)h2v;
        }
    }
    #pragma unroll
    for (int off = 32; off >= 1; off >>= 1) local += __shfl_down(local, off, 64);
    if (lane == 0) wsum[wave] = local;
    __syncthreads();

    float tot   = wsum[0] + wsum[1] + wsum[2] + wsum[3];
    float mean  = tot * (1.f / 15.f) * (1.f / ((float)NQ * (float)NQ));
    float inv   = 1.f / (mean + 1e-6f);
    float b2bar = 0.125f * (b2[0] + b2[1] + b2[2] + b2[3] +
                            b2[4] + b2[5] + b2[6] + b2[7]);
    float lam   = lam_p[0];

    // my half of the LUT: one pass per thread (226 or 225 entries <= 256)
    {
        int s0  = half * 226;
        int cnt = half ? 225 : 226;
        if (tid < cnt) {
            int   s   = s0 + tid;
            float t   = sqs[s] * (1.f / 15.f) * inv;
            float acc = b2bar;
            for (int i = 0; i < 256; ++i) {
                float hv = fmaf(t, w1s[i], b1s[i]);
                acc = fmaf(fmaxf(hv, 0.f), wbars[i], acc);
            }
            lutp[b * LUT_N + s] = lam * acc;    // plain store; boundary syncs
        }
    }
    if (half == 0 && tid < 225) {               // pack centers u8x4 once
        centp[b * 225 + tid] = (idx_s[4*tid] & 255) |
                               ((idx_s[4*tid+1] & 255) << 8) |
                               ((idx_s[4*tid+2] & 255) << 16) |
                               ((idx_s[4*tid+3] & 255) << 24);
    }
}

__global__ __launch_bounds__(256)
void k2_apply(const float* __restrict__ attn,
              const int* __restrict__ ws,
              float* __restrict__ out) {
    const float* lutp  = (const float*)(ws + 900);
    const int*   centp = ws + 900 + 2 * LUT_N;
    const int b = blockIdx.y;

    __shared__ float lut_s[LUT_N];
    __shared__ int   cpk[225];                  // packed centers (word t: q 4t..4t+3)
    if (threadIdx.x < 225) cpk[threadIdx.x] = centp[b * 225 + threadIdx.x];
    for (int s = threadIdx.x; s < LUT_N; s += 256) lut_s[s] = lutp[b * LUT_N + s];
    __syncthreads();

    // 4 float4 per thread, 1024 f4 per block, 198 blocks per batch
    const int base_f4 = blockIdx.x * 1024 + threadIdx.x;
    #pragma unroll
    for (int u = 0; u < 4; ++u) {
        int f4 = base_f4 + u * 256;
        if (f4 < 202500) {
            int i  = f4 / 225;                  // row
            int j4 = f4 - i * 225;              // float4 within row (cols 4j4..)
            int ci = (cpk[i >> 2] >> ((i & 3) * 8)) & 255;   // mostly broadcast
            int ixi = ci & 15, iyi = ci >> 4;
            int cw = cpk[j4];                   // stride-1, conflict-free
            size_t g = (size_t)b * (NQ * NQ) + (size_t)i * NQ + j4 * 4;
            float4 a = *(const float4*)(attn + g);
            int c, dx, dy;
            c = cw & 255;         dx = ixi - (c & 15); dy = iyi - (c >> 4); a.x += lut_s[dx*dx + dy*dy];
            c = (cw >> 8) & 255;  dx = ixi - (c & 15); dy = iyi - (c >> 4); a.y += lut_s[dx*dx + dy*dy];
            c = (cw >> 16) & 255; dx = ixi - (c & 15); dy = iyi - (c >> 4); a.z += lut_s[dx*dx + dy*dy];
            c = (cw >> 24) & 255; dx = ixi - (c & 15); dy = iyi - (c >> 4); a.w += lut_s[dx*dx + dy*dy];
            *(float4*)(out + g) = a;
        }
    }
}

extern "C" void kernel_launch(void* const* d_in, const int* in_sizes, int n_in,
                              void* d_out, int out_size, void* d_ws, size_t ws_size,
                              hipStream_t stream) {
    const float* attn = (const float*)d_in[0];   // [2,900,900]
    const float* ref  = (const float*)d_in[1];   // [2,900,16,16]
    const float* lam  = (const float*)d_in[2];
    const float* w1   = (const float*)d_in[3];   // [256]
    const float* b1   = (const float*)d_in[4];   // [256]
    const float* w2   = (const float*)d_in[5];   // [256,8]
    const float* b2   = (const float*)d_in[6];   // [8]
    float* out = (float*)d_out;
    int*   ws  = (int*)d_ws;                     // cent2[900]|lutp[902]|centp[450]

    k1_centers_stats<<<454, 256, 0, stream>>>(ref, lam, w1, b1, w2, b2, ws);
    k2_apply<<<dim3(198, 2), 256, 0, stream>>>(attn, ws, out);
}